// Round 1
// 398.338 us; speedup vs baseline: 1.4757x; 1.4757x over previous
//
#include <hip/hip_runtime.h>
#include <math.h>

#define IMG_W   800
#define IMG_PIX (IMG_W * IMG_W)
#define NEDGE   6000
#define NSRC    4
#define NVIEW   5
// d_out layout (floats):
//   sim loss : [0, NSRC*NEDGE)
//   mask     : [NSRC*NEDGE, 2*NSRC*NEDGE)
//   black    : [2*NSRC*NEDGE, 2*NSRC*NEDGE + NEDGE)
//   p2d1     : [HDR, HDR + 2P)
//   p2d2     : [HDR + 2P, HDR + 10P)
#define HDR (2 * NSRC * NEDGE + NEDGE) // 54000

typedef float vf4 __attribute__((ext_vector_type(4)));
typedef float vf2 __attribute__((ext_vector_type(2)));

// 8-byte image-row pair, only 4-byte aligned.
struct __attribute__((packed, aligned(4))) f2u { float a, b; };

__device__ __forceinline__ f2u ld2(const float* __restrict__ p) {
    return *(const f2u*)p;
}
__device__ __forceinline__ void nts2(float* p, float a, float b) {
    vf2 v; v.x = a; v.y = b;
    __builtin_nontemporal_store(v, (vf2*)p);
}
__device__ __forceinline__ void nts4(float* p, float a, float b, float c, float d) {
    vf4 v; v.x = a; v.y = b; v.z = c; v.w = d;
    __builtin_nontemporal_store(v, (vf4*)p);
}

// Kernel A: per-edge, per-view projection params (packed 2x float4 per view).
__global__ void edge_params(const float* __restrict__ sp,
                            const float* __restrict__ epnt,
                            const float* __restrict__ K,
                            const float* __restrict__ T,
                            float4* __restrict__ prm) {
    int e = blockIdx.x * blockDim.x + threadIdx.x;
    if (e >= NEDGE) return;
    float sx = sp[3 * e], sy = sp[3 * e + 1], sz = sp[3 * e + 2];
    float ex = epnt[3 * e], ey = epnt[3 * e + 1], ez = epnt[3 * e + 2];
    for (int v = 0; v < NVIEW; ++v) {
        float as, bs, cs, ae, be, ce;
        if (v == 0) {
            as = K[0] * sx + K[1] * sy + K[2] * sz;
            bs = K[3] * sx + K[4] * sy + K[5] * sz;
            cs = K[6] * sx + K[7] * sy + K[8] * sz;
            ae = K[0] * ex + K[1] * ey + K[2] * ez;
            be = K[3] * ex + K[4] * ey + K[5] * ez;
            ce = K[6] * ex + K[7] * ey + K[8] * ez;
        } else {
            const float* t = T + (v - 1) * 12;
            as = t[0] * sx + t[1] * sy + t[2] * sz + t[3];
            bs = t[4] * sx + t[5] * sy + t[6] * sz + t[7];
            cs = t[8] * sx + t[9] * sy + t[10] * sz + t[11];
            ae = t[0] * ex + t[1] * ey + t[2] * ez + t[3];
            be = t[4] * ex + t[5] * ey + t[6] * ez + t[7];
            ce = t[8] * ex + t[9] * ey + t[10] * ez + t[11];
        }
        float u0 = as / (cs + 1e-6f);
        float w0 = bs / (cs + 1e-6f);
        float u1 = ae / (ce + 1e-6f);
        float w1 = be / (ce + 1e-6f);
        float dx = u1 - u0, dy = w1 - w0;
        float cxx = dy, cyy = -dx;   // cross([dx,dy,0],[0,0,1])
        float nrm = sqrtf(cxx * cxx + cyy * cyy);
        float inv = 1.f / (nrm + 1e-6f) * (10.0f / (float)IMG_W);
        prm[(e * NVIEW + v) * 2 + 0] = make_float4(u0, w0, dx, dy);
        prm[(e * NVIEW + v) * 2 + 1] = make_float4(cxx * inv, cyy * inv, 0.f, 0.f);
    }
}

// Kernel A2: exclusive prefix sum of num_per_edge -> per-edge point offsets.
__global__ void __launch_bounds__(256)
scan_kernel(const int* __restrict__ npe, int* __restrict__ bg) {
    __shared__ int part[256];
    int t = threadIdx.x;
    int base = t * 24;            // 256*24 = 6144 >= 6000
    int loc[24];
    int s = 0;
#pragma unroll
    for (int i = 0; i < 24; ++i) {
        int idx = base + i;
        int v = (idx < NEDGE) ? npe[idx] : 0;
        loc[i] = s;
        s += v;
    }
    part[t] = s;
    __syncthreads();
    int own = s;
    for (int off = 1; off < 256; off <<= 1) {
        int v = (t >= off) ? part[t - off] : 0;
        __syncthreads();
        part[t] += v;
        __syncthreads();
    }
    int myoff = part[t] - own;    // exclusive prefix of this thread's chunk
#pragma unroll
    for (int i = 0; i < 24; ++i) {
        int idx = base + i;
        if (idx < NEDGE) bg[idx] = myoff + loc[i];
    }
}

// Kernel B: one block per edge. Coords computed on-device (bit-exact vs numpy:
// IEEE double divide then cast to f32). Block-reduce sums/mask, fused finalize.
// Point->thread remap: thread t owns points {2t,2t+1, 512+2t, 513+2t} of each
// 1024-point chunk so each NT store instruction is lane-contiguous (full 64B
// line coverage within one wave store -> no partial-line write amplification).
__global__ void __launch_bounds__(256)
points_kernel(const int* __restrict__ npe,
              const int* __restrict__ bg,
              const float* __restrict__ imgs,
              const float4* __restrict__ prm,
              float* __restrict__ out,
              int P) {
    const int e = blockIdx.x;
    const int nsamp = npe[e];          // num_h * 20
    const int nh = nsamp / 20;
    const int b20 = bg[e];

    __shared__ float DX[1000];         // num_h clipped to [2,1000]
    __shared__ float DY[20];
    __shared__ float rS[4][5];
    __shared__ int   rM[4];

    for (int h = threadIdx.x; h < nh; h += 256)
        DX[h] = (float)((double)h / (double)(nh - 1));
    if (threadIdx.x < 20) {
        int m = threadIdx.x;
        DY[m] = (m < 10) ? -(float)((double)(9 - m) / 9.0)
                         :  (float)((double)(m - 10) / 9.0);
    }

    // Wave-uniform per-edge params (e = blockIdx) -> scalar loads.
    float4 A[NVIEW], B[NVIEW];
    {
        const float4* pe = prm + (size_t)e * (NVIEW * 2);
#pragma unroll
        for (int v = 0; v < NVIEW; ++v) { A[v] = pe[2 * v]; B[v] = pe[2 * v + 1]; }
    }
    __syncthreads();

    float accs[NSRC] = {0.f, 0.f, 0.f, 0.f};
    float accB = 0.f;
    unsigned maskAcc = 0x1Fu;

    for (int base = 0; base < nsamp; base += 256 * 4) {
        const int t = threadIdx.x;
        bool fullIter = (base + 1024) <= nsamp;
        if (fullIter) {
            // points owned by this thread
            int pidx[4];
            pidx[0] = base + 2 * t;
            pidx[1] = pidx[0] + 1;
            pidx[2] = pidx[0] + 512;
            pidx[3] = pidx[2] + 1;

            float px[4 * NVIEW], py[4 * NVIEW];
            unsigned vmb[4];
#pragma unroll
            for (int k = 0; k < 4; ++k) {
                int p = pidx[k];
                int h = p / 20;
                int m = p - h * 20;
                float xk = DX[h];
                float yk = DY[m];
                unsigned mb = 0;
#pragma unroll
                for (int v = 0; v < NVIEW; ++v) {
                    float ux = A[v].z * xk + B[v].x * yk + A[v].x;
                    float uy = A[v].w * xk + B[v].y * yk + A[v].y;
                    if ((ux > 0.f) && (ux < 1.f) && (uy > 0.f) && (uy < 1.f)) mb |= (1u << v);
                    px[k * NVIEW + v] = fminf(fmaxf(ux, 0.f), 0.999999f);
                    py[k * NVIEW + v] = fminf(fmaxf(uy, 0.f), 0.999999f);
                }
                vmb[k] = mb;
                maskAcc &= mb;
            }

            // p2d streaming stores: lane-contiguous within each instruction
            size_t gb = (size_t)(b20 + base);
#pragma unroll
            for (int v = 0; v < NVIEW; ++v) {
                float* bp = (v == 0) ? (out + HDR + 2 * gb)
                                     : (out + HDR + 2 * (size_t)P
                                            + 2 * ((size_t)(v - 1) * P + gb));
                nts4(bp + 4 * t,        px[0 * NVIEW + v], py[0 * NVIEW + v],
                                        px[1 * NVIEW + v], py[1 * NVIEW + v]);
                nts4(bp + 1024 + 4 * t, px[2 * NVIEW + v], py[2 * NVIEW + v],
                                        px[3 * NVIEW + v], py[3 * NVIEW + v]);
            }

            // issue all 40 row-pair gathers; px/py -> wx/wy in place
            f2u r0[4 * NVIEW], r1[4 * NVIEW];
            unsigned hib[4] = {0, 0, 0, 0};
#pragma unroll
            for (int k = 0; k < 4; ++k) {
#pragma unroll
                for (int v = 0; v < NVIEW; ++v) {
                    int j = k * NVIEW + v;
                    float fx = px[j] * (float)IMG_W - 0.5f;
                    float fy = py[j] * (float)IMG_W - 0.5f;
                    float xf = floorf(fx), yf = floorf(fy);
                    px[j] = fx - xf;
                    py[j] = fy - yf;
                    int x0 = (int)xf;
                    int y0 = (int)yf;
                    int xc = min(max(x0, 0), IMG_W - 2);
                    int y0i = min(max(y0, 0), IMG_W - 1);
                    int y1i = min(y0i + 1, IMG_W - 1);
                    if (x0 >= IMG_W - 1) hib[k] |= (1u << v);
                    const float* im = imgs + v * IMG_PIX;
                    r0[j] = ld2(im + y0i * IMG_W + xc);
                    r1[j] = ld2(im + y1i * IMG_W + xc);
                }
            }
            // combine + accumulate (all points belong to edge e)
#pragma unroll
            for (int k = 0; k < 4; ++k) {
                float sval[NVIEW];
#pragma unroll
                for (int v = 0; v < NVIEW; ++v) {
                    int j = k * NVIEW + v;
                    bool hi = (hib[k] >> v) & 1u;
                    float v00 = hi ? r0[j].b : r0[j].a;
                    float v01 = r0[j].b;
                    float v10 = hi ? r1[j].b : r1[j].a;
                    float v11 = r1[j].b;
                    float wxv = px[j], wyv = py[j];
                    sval[v] = (v00 * (1.f - wxv) + v01 * wxv) * (1.f - wyv)
                            + (v10 * (1.f - wxv) + v11 * wxv) * wyv;
                }
                float s1 = sval[0];
                accB += (s1 < 0.01f) ? 1.f : 0.f;
#pragma unroll
                for (int s = 0; s < NSRC; ++s) {
                    float d = sval[s + 1] - s1;
                    accs[s] += d * d;
                }
            }
        } else {
            // tail chunk: scalar per-point path, same ownership pattern
            int pidx[4];
            pidx[0] = base + 2 * t;
            pidx[1] = pidx[0] + 1;
            pidx[2] = pidx[0] + 512;
            pidx[3] = pidx[2] + 1;
#pragma unroll
            for (int k = 0; k < 4; ++k) {
                int p = pidx[k];
                if (p >= nsamp) continue;
                int h = p / 20;
                int m = p - h * 20;
                float xk = DX[h];
                float yk = DY[m];
                unsigned mb = 0;
                float lpx[NVIEW], lpy[NVIEW];
#pragma unroll
                for (int v = 0; v < NVIEW; ++v) {
                    float ux = A[v].z * xk + B[v].x * yk + A[v].x;
                    float uy = A[v].w * xk + B[v].y * yk + A[v].y;
                    if ((ux > 0.f) && (ux < 1.f) && (uy > 0.f) && (uy < 1.f)) mb |= (1u << v);
                    lpx[v] = fminf(fmaxf(ux, 0.f), 0.999999f);
                    lpy[v] = fminf(fmaxf(uy, 0.f), 0.999999f);
                }
                maskAcc &= mb;
                size_t g = (size_t)(b20 + p);
                nts2(out + HDR + 2 * g, lpx[0], lpy[0]);
#pragma unroll
                for (int s = 0; s < NSRC; ++s)
                    nts2(out + HDR + 2 * (size_t)P + 2 * ((size_t)s * P + g),
                         lpx[s + 1], lpy[s + 1]);
                float sval[NVIEW];
#pragma unroll
                for (int v = 0; v < NVIEW; ++v) {
                    float fx = lpx[v] * (float)IMG_W - 0.5f;
                    float fy = lpy[v] * (float)IMG_W - 0.5f;
                    float xf = floorf(fx), yf = floorf(fy);
                    float wxv = fx - xf, wyv = fy - yf;
                    int x0 = (int)xf;
                    int y0 = (int)yf;
                    int xc = min(max(x0, 0), IMG_W - 2);
                    int y0i = min(max(y0, 0), IMG_W - 1);
                    int y1i = min(y0i + 1, IMG_W - 1);
                    bool hi = (x0 >= IMG_W - 1);
                    const float* im = imgs + v * IMG_PIX;
                    f2u a = ld2(im + y0i * IMG_W + xc);
                    f2u b = ld2(im + y1i * IMG_W + xc);
                    float v00 = hi ? a.b : a.a;
                    float v01 = a.b;
                    float v10 = hi ? b.b : b.a;
                    float v11 = b.b;
                    sval[v] = (v00 * (1.f - wxv) + v01 * wxv) * (1.f - wyv)
                            + (v10 * (1.f - wxv) + v11 * wxv) * wyv;
                }
                float s1 = sval[0];
                accB += (s1 < 0.01f) ? 1.f : 0.f;
#pragma unroll
                for (int s = 0; s < NSRC; ++s) {
                    float d = sval[s + 1] - s1;
                    accs[s] += d * d;
                }
            }
        }
    }

    // ---- block reduction: wave shuffles then LDS across 4 waves ----
    int lane = threadIdx.x & 63, wid = threadIdx.x >> 6;
    int mi = (int)maskAcc;
#pragma unroll
    for (int off = 32; off > 0; off >>= 1) {
        accs[0] += __shfl_down(accs[0], off);
        accs[1] += __shfl_down(accs[1], off);
        accs[2] += __shfl_down(accs[2], off);
        accs[3] += __shfl_down(accs[3], off);
        accB    += __shfl_down(accB, off);
        mi      &= __shfl_down(mi, off);
    }
    if (lane == 0) {
        rS[wid][0] = accs[0]; rS[wid][1] = accs[1];
        rS[wid][2] = accs[2]; rS[wid][3] = accs[3];
        rS[wid][4] = accB;
        rM[wid] = mi;
    }
    __syncthreads();
    if (threadIdx.x == 0) {
        float s0 = 0.f, s1 = 0.f, s2 = 0.f, s3 = 0.f, sB = 0.f;
        int m = 0x1F;
#pragma unroll
        for (int w = 0; w < 4; ++w) {
            s0 += rS[w][0]; s1 += rS[w][1]; s2 += rS[w][2]; s3 += rS[w][3];
            sB += rS[w][4];
            m  &= rM[w];
        }
        float cnt = (float)nsamp;
        out[0 * NEDGE + e] = s0 / cnt;
        out[1 * NEDGE + e] = s1 / cnt;
        out[2 * NEDGE + e] = s2 / cnt;
        out[3 * NEDGE + e] = s3 / cnt;
        bool vm1 = m & 1;
#pragma unroll
        for (int s = 0; s < NSRC; ++s)
            out[NSRC * NEDGE + s * NEDGE + e] =
                (vm1 && ((m >> (s + 1)) & 1)) ? 1.f : 0.f;
        out[2 * NSRC * NEDGE + e] = ((sB / cnt) > 0.5f) ? 1.f : 0.f;
    }
}

extern "C" void kernel_launch(void* const* d_in, const int* in_sizes, int n_in,
                              void* d_out, int out_size, void* d_ws, size_t ws_size,
                              hipStream_t stream) {
    const float* start = (const float*)d_in[0];
    const float* endp  = (const float*)d_in[1];
    const float* imgs  = (const float*)d_in[2];
    const float* trans = (const float*)d_in[3];
    const float* K     = (const float*)d_in[4];
    const int*   npe   = (const int*)d_in[8];
    int P = in_sizes[5];

    float4* prm = (float4*)d_ws;                                   // 960000 B
    int*    bg  = (int*)((char*)d_ws + NEDGE * NVIEW * 2 * 16);    // 24000 B

    float* out = (float*)d_out;
    edge_params<<<(NEDGE + 255) / 256, 256, 0, stream>>>(start, endp, K, trans, prm);
    scan_kernel<<<1, 256, 0, stream>>>(npe, bg);
    points_kernel<<<NEDGE, 256, 0, stream>>>(npe, bg, imgs, prm, out, P);
}

// Round 3
// 385.015 us; speedup vs baseline: 1.5267x; 1.0346x over previous
//
#include <hip/hip_runtime.h>
#include <math.h>

#define IMG_W   800
#define IMG_PIX (IMG_W * IMG_W)
#define NEDGE   6000
#define NSRC    4
#define NVIEW   5
// d_out layout (floats):
//   sim loss : [0, NSRC*NEDGE)
//   mask     : [NSRC*NEDGE, 2*NSRC*NEDGE)
//   black    : [2*NSRC*NEDGE, 2*NSRC*NEDGE + NEDGE)
//   p2d1     : [HDR, HDR + 2P)
//   p2d2     : [HDR + 2P, HDR + 10P)
#define HDR (2 * NSRC * NEDGE + NEDGE) // 54000

typedef float vf4 __attribute__((ext_vector_type(4)));
typedef float vf2 __attribute__((ext_vector_type(2)));

// 8-byte image-row pair, only 4-byte aligned.
struct __attribute__((packed, aligned(4))) f2u { float a, b; };

__device__ __forceinline__ f2u ld2(const float* __restrict__ p) {
    return *(const f2u*)p;
}
// readfirstlane for float MUST go through bitcasts: the builtin is int(int),
// so a float argument would be numerically truncated (round-2 bug).
__device__ __forceinline__ float rfl(float x) {
    return __uint_as_float((unsigned)__builtin_amdgcn_readfirstlane(
        (int)__float_as_uint(x)));
}
// 16B store; nt (wave-uniform) selects non-temporal vs cached.
// Misaligned (32B-offset) streams use cached stores so L2 merges the partial
// 64B lines; NT partial lines go to HBM twice (measured 1.5x WRITE).
__device__ __forceinline__ void st4(float* p, float a, float b, float c, float d,
                                    bool nt) {
    vf4 v; v.x = a; v.y = b; v.z = c; v.w = d;
    if (nt) __builtin_nontemporal_store(v, (vf4*)p);
    else    *(vf4*)p = v;
}

// Kernel A: per-edge, per-view projection params (packed 2x float4 per view).
__global__ void edge_params(const float* __restrict__ sp,
                            const float* __restrict__ epnt,
                            const float* __restrict__ K,
                            const float* __restrict__ T,
                            float4* __restrict__ prm) {
    int e = blockIdx.x * blockDim.x + threadIdx.x;
    if (e >= NEDGE) return;
    float sx = sp[3 * e], sy = sp[3 * e + 1], sz = sp[3 * e + 2];
    float ex = epnt[3 * e], ey = epnt[3 * e + 1], ez = epnt[3 * e + 2];
    for (int v = 0; v < NVIEW; ++v) {
        float as, bs, cs, ae, be, ce;
        if (v == 0) {
            as = K[0] * sx + K[1] * sy + K[2] * sz;
            bs = K[3] * sx + K[4] * sy + K[5] * sz;
            cs = K[6] * sx + K[7] * sy + K[8] * sz;
            ae = K[0] * ex + K[1] * ey + K[2] * ez;
            be = K[3] * ex + K[4] * ey + K[5] * ez;
            ce = K[6] * ex + K[7] * ey + K[8] * ez;
        } else {
            const float* t = T + (v - 1) * 12;
            as = t[0] * sx + t[1] * sy + t[2] * sz + t[3];
            bs = t[4] * sx + t[5] * sy + t[6] * sz + t[7];
            cs = t[8] * sx + t[9] * sy + t[10] * sz + t[11];
            ae = t[0] * ex + t[1] * ey + t[2] * ez + t[3];
            be = t[4] * ex + t[5] * ey + t[6] * ez + t[7];
            ce = t[8] * ex + t[9] * ey + t[10] * ez + t[11];
        }
        float u0 = as / (cs + 1e-6f);
        float w0 = bs / (cs + 1e-6f);
        float u1 = ae / (ce + 1e-6f);
        float w1 = be / (ce + 1e-6f);
        float dx = u1 - u0, dy = w1 - w0;
        float cxx = dy, cyy = -dx;   // cross([dx,dy,0],[0,0,1])
        float nrm = sqrtf(cxx * cxx + cyy * cyy);
        float inv = 1.f / (nrm + 1e-6f) * (10.0f / (float)IMG_W);
        prm[(e * NVIEW + v) * 2 + 0] = make_float4(u0, w0, dx, dy);
        prm[(e * NVIEW + v) * 2 + 1] = make_float4(cxx * inv, cyy * inv, 0.f, 0.f);
    }
}

// Kernel A2: exclusive prefix sum of num_per_edge -> per-edge point offsets.
__global__ void __launch_bounds__(256)
scan_kernel(const int* __restrict__ npe, int* __restrict__ bg) {
    __shared__ int part[256];
    int t = threadIdx.x;
    int base = t * 24;            // 256*24 = 6144 >= 6000
    int loc[24];
    int s = 0;
#pragma unroll
    for (int i = 0; i < 24; ++i) {
        int idx = base + i;
        int v = (idx < NEDGE) ? npe[idx] : 0;
        loc[i] = s;
        s += v;
    }
    part[t] = s;
    __syncthreads();
    int own = s;
    for (int off = 1; off < 256; off <<= 1) {
        int v = (t >= off) ? part[t - off] : 0;
        __syncthreads();
        part[t] += v;
        __syncthreads();
    }
    int myoff = part[t] - own;    // exclusive prefix of this thread's chunk
#pragma unroll
    for (int i = 0; i < 24; ++i) {
        int idx = base + i;
        if (idx < NEDGE) bg[idx] = myoff + loc[i];
    }
}

// Kernel B: one block per edge, 512-point chunks, 2 points/thread.
// nsamp is even => p0 valid implies p1 valid: single predicate, no scalar
// tail path. Per-(edge,view) 64B-alignment selects NT vs cached stores.
// Edge params forced to SGPRs via bitcast readfirstlane (wave-uniform).
__global__ void __launch_bounds__(256)
points_kernel(const int* __restrict__ npe,
              const int* __restrict__ bg,
              const float* __restrict__ imgs,
              const float* __restrict__ prm,
              float* __restrict__ out,
              int P) {
    const int e = blockIdx.x;
    const int nsamp = npe[e];          // num_h * 20, even, >= 40
    const int nh = nsamp / 20;
    const int b20 = bg[e];

    __shared__ float DX[1000];         // num_h clipped to [2,1000]
    __shared__ float DY[20];
    __shared__ float rS[4][5];
    __shared__ int   rM[4];

    for (int h = threadIdx.x; h < nh; h += 256)
        DX[h] = (float)((double)h / (double)(nh - 1));
    if (threadIdx.x < 20) {
        int m = threadIdx.x;
        DY[m] = (m < 10) ? -(float)((double)(9 - m) / 9.0)
                         :  (float)((double)(m - 10) / 9.0);
    }

    // Wave-uniform per-edge params -> SGPRs (bitcast readfirstlane).
    float Ax[NVIEW], Ay[NVIEW], Az[NVIEW], Aw[NVIEW], Bx[NVIEW], By[NVIEW];
    {
        const float* pe = prm + (size_t)e * (NVIEW * 8);
#pragma unroll
        for (int v = 0; v < NVIEW; ++v) {
            Ax[v] = rfl(pe[8 * v + 0]);
            Ay[v] = rfl(pe[8 * v + 1]);
            Az[v] = rfl(pe[8 * v + 2]);
            Aw[v] = rfl(pe[8 * v + 3]);
            Bx[v] = rfl(pe[8 * v + 4]);
            By[v] = rfl(pe[8 * v + 5]);
        }
    }

    // Per-view store bases + 64B-alignment flags (constant across iters:
    // base advances by 512 pts = 4096B).
    float* vbase[NVIEW];
    bool   val64[NVIEW];
    {
        size_t gb = (size_t)b20;
        vbase[0] = out + HDR + 2 * gb;
#pragma unroll
        for (int s = 0; s < NSRC; ++s)
            vbase[s + 1] = out + HDR + 2 * (size_t)P + 2 * ((size_t)s * P + gb);
#pragma unroll
        for (int v = 0; v < NVIEW; ++v)
            val64[v] = ((((size_t)vbase[v]) & 63) == 0);
    }
    __syncthreads();

    float accs[NSRC] = {0.f, 0.f, 0.f, 0.f};
    float accB = 0.f;
    unsigned maskAcc = 0x1Fu;

    const int t = threadIdx.x;
    for (int base = 0; base < nsamp; base += 512) {
        int p0 = base + 2 * t;
        bool valid = (p0 < nsamp);     // nsamp even => p0+1 also valid

        float px[2 * NVIEW], py[2 * NVIEW];
        if (valid) {
#pragma unroll
            for (int k = 0; k < 2; ++k) {
                int p = p0 + k;
                int h = p / 20;
                int m = p - h * 20;
                float xk = DX[h];
                float yk = DY[m];
                unsigned mb = 0;
#pragma unroll
                for (int v = 0; v < NVIEW; ++v) {
                    float ux = Az[v] * xk + Bx[v] * yk + Ax[v];
                    float uy = Aw[v] * xk + By[v] * yk + Ay[v];
                    if ((ux > 0.f) && (ux < 1.f) && (uy > 0.f) && (uy < 1.f))
                        mb |= (1u << v);
                    px[k * NVIEW + v] = fminf(fmaxf(ux, 0.f), 0.999999f);
                    py[k * NVIEW + v] = fminf(fmaxf(uy, 0.f), 0.999999f);
                }
                maskAcc &= mb;
            }

            // p2d stores: lane-contiguous 16B per lane.
#pragma unroll
            for (int v = 0; v < NVIEW; ++v) {
                st4(vbase[v] + 2 * base + 4 * t,
                    px[0 * NVIEW + v], py[0 * NVIEW + v],
                    px[1 * NVIEW + v], py[1 * NVIEW + v], val64[v]);
            }

            // issue all 20 row-pair gathers; px/py -> wx/wy in place
            f2u r0[2 * NVIEW], r1[2 * NVIEW];
            unsigned hib = 0;
#pragma unroll
            for (int k = 0; k < 2; ++k) {
#pragma unroll
                for (int v = 0; v < NVIEW; ++v) {
                    int j = k * NVIEW + v;
                    float fx = px[j] * (float)IMG_W - 0.5f;
                    float fy = py[j] * (float)IMG_W - 0.5f;
                    float xf = floorf(fx), yf = floorf(fy);
                    px[j] = fx - xf;
                    py[j] = fy - yf;
                    int x0 = (int)xf;
                    int y0 = (int)yf;
                    int xc = min(max(x0, 0), IMG_W - 2);
                    int y0i = min(max(y0, 0), IMG_W - 1);
                    int y1i = min(y0i + 1, IMG_W - 1);
                    if (x0 >= IMG_W - 1) hib |= (1u << j);
                    const float* im = imgs + v * IMG_PIX;
                    r0[j] = ld2(im + y0i * IMG_W + xc);
                    r1[j] = ld2(im + y1i * IMG_W + xc);
                }
            }
            // combine + accumulate
#pragma unroll
            for (int k = 0; k < 2; ++k) {
                float sval[NVIEW];
#pragma unroll
                for (int v = 0; v < NVIEW; ++v) {
                    int j = k * NVIEW + v;
                    bool hi = (hib >> j) & 1u;
                    float v00 = hi ? r0[j].b : r0[j].a;
                    float v01 = r0[j].b;
                    float v10 = hi ? r1[j].b : r1[j].a;
                    float v11 = r1[j].b;
                    float wxv = px[j], wyv = py[j];
                    sval[v] = (v00 * (1.f - wxv) + v01 * wxv) * (1.f - wyv)
                            + (v10 * (1.f - wxv) + v11 * wxv) * wyv;
                }
                float s1 = sval[0];
                accB += (s1 < 0.01f) ? 1.f : 0.f;
#pragma unroll
                for (int s = 0; s < NSRC; ++s) {
                    float d = sval[s + 1] - s1;
                    accs[s] += d * d;
                }
            }
        }
    }

    // ---- block reduction: wave shuffles then LDS across 4 waves ----
    int lane = threadIdx.x & 63, wid = threadIdx.x >> 6;
    int mi = (int)maskAcc;
#pragma unroll
    for (int off = 32; off > 0; off >>= 1) {
        accs[0] += __shfl_down(accs[0], off);
        accs[1] += __shfl_down(accs[1], off);
        accs[2] += __shfl_down(accs[2], off);
        accs[3] += __shfl_down(accs[3], off);
        accB    += __shfl_down(accB, off);
        mi      &= __shfl_down(mi, off);
    }
    if (lane == 0) {
        rS[wid][0] = accs[0]; rS[wid][1] = accs[1];
        rS[wid][2] = accs[2]; rS[wid][3] = accs[3];
        rS[wid][4] = accB;
        rM[wid] = mi;
    }
    __syncthreads();
    if (threadIdx.x == 0) {
        float s0 = 0.f, s1 = 0.f, s2 = 0.f, s3 = 0.f, sB = 0.f;
        int m = 0x1F;
#pragma unroll
        for (int w = 0; w < 4; ++w) {
            s0 += rS[w][0]; s1 += rS[w][1]; s2 += rS[w][2]; s3 += rS[w][3];
            sB += rS[w][4];
            m  &= rM[w];
        }
        float cnt = (float)nsamp;
        out[0 * NEDGE + e] = s0 / cnt;
        out[1 * NEDGE + e] = s1 / cnt;
        out[2 * NEDGE + e] = s2 / cnt;
        out[3 * NEDGE + e] = s3 / cnt;
        bool vm1 = m & 1;
#pragma unroll
        for (int s = 0; s < NSRC; ++s)
            out[NSRC * NEDGE + s * NEDGE + e] =
                (vm1 && ((m >> (s + 1)) & 1)) ? 1.f : 0.f;
        out[2 * NSRC * NEDGE + e] = ((sB / cnt) > 0.5f) ? 1.f : 0.f;
    }
}

extern "C" void kernel_launch(void* const* d_in, const int* in_sizes, int n_in,
                              void* d_out, int out_size, void* d_ws, size_t ws_size,
                              hipStream_t stream) {
    const float* start = (const float*)d_in[0];
    const float* endp  = (const float*)d_in[1];
    const float* imgs  = (const float*)d_in[2];
    const float* trans = (const float*)d_in[3];
    const float* K     = (const float*)d_in[4];
    const int*   npe   = (const int*)d_in[8];
    int P = in_sizes[5];

    float4* prm = (float4*)d_ws;                                   // 960000 B
    int*    bg  = (int*)((char*)d_ws + NEDGE * NVIEW * 2 * 16);    // 24000 B

    float* out = (float*)d_out;
    edge_params<<<(NEDGE + 255) / 256, 256, 0, stream>>>(start, endp, K, trans, prm);
    scan_kernel<<<1, 256, 0, stream>>>(npe, bg);
    points_kernel<<<NEDGE, 256, 0, stream>>>(npe, bg, imgs, (const float*)prm, out, P);
}